// Round 2
// baseline (857.699 us; speedup 1.0000x reference)
//
#include <hip/hip_runtime.h>
#include <cstdint>

#define T_STEPS 200
#define B_TOTAL 8192
#define F_IN    40
#define H_DIM   128
#define C_OUT   5

// ---------------------------------------------------------------------------
// Kernel A: layer-1 leaky recurrence. Exact fp32 emulation of numpy/BLAS:
//   cur1 = sequential-f FMA chain (acc starts 0), then + b1 (rounded add)
//   m1   = ((0.9f*m1) + cur1) - reset   (each op individually rounded)
// One wave per batch element; lane li owns h = li and h = li+64 so the two
// __ballot results are exactly the 128-bit spike mask in ascending-h order.
// ---------------------------------------------------------------------------
__global__ __launch_bounds__(256) void snn_l1(const float* __restrict__ x,
                                              const float* __restrict__ w1,
                                              const float* __restrict__ b1,
                                              ulonglong2* __restrict__ masks)
{
    const int li = threadIdx.x & 63;
    const int wv = threadIdx.x >> 6;
    const int b  = blockIdx.x * 4 + wv;      // grid 2048 -> b in [0,8192)
    const int hA = li, hB = li + 64;

    // w1 rows for this lane's two h, register-resident (80 VGPRs)
    float wA[F_IN], wB[F_IN];
    const float4* w1v = (const float4*)w1;
#pragma unroll
    for (int q = 0; q < 10; ++q) {
        float4 a = w1v[hA * 10 + q];
        wA[4*q+0] = a.x; wA[4*q+1] = a.y; wA[4*q+2] = a.z; wA[4*q+3] = a.w;
        float4 c = w1v[hB * 10 + q];
        wB[4*q+0] = c.x; wB[4*q+1] = c.y; wB[4*q+2] = c.z; wB[4*q+3] = c.w;
    }
    const float b1A = b1[hA], b1B = b1[hB];
    float mA = 0.0f, mB = 0.0f, rA = 0.0f, rB = 0.0f;

    // x row double-buffer (wave-uniform broadcast loads)
    const float4* xv = (const float4*)(x + (size_t)b * T_STEPS * F_IN);
    float4 xc[10], xn[10];
#pragma unroll
    for (int q = 0; q < 10; ++q) xc[q] = xv[q];   // row t=0

    auto substep = [&](float4 (&cur)[10], float4 (&oth)[10], int t) {
        // prefetch next row (clamped reload of last row at the tail; harmless)
        const int tn = (t + 1 < T_STEPS) ? t + 1 : T_STEPS - 1;
#pragma unroll
        for (int q = 0; q < 10; ++q) oth[q] = xv[(size_t)tn * 10 + q];

        // sequential-f FMA dot, exactly BLAS order (f = 0..39 ascending)
        float a0 = 0.0f, a1 = 0.0f;
#pragma unroll
        for (int q = 0; q < 10; ++q) {
            const float4 xq = cur[q];
            a0 = __fmaf_rn(xq.x, wA[4*q+0], a0);
            a0 = __fmaf_rn(xq.y, wA[4*q+1], a0);
            a0 = __fmaf_rn(xq.z, wA[4*q+2], a0);
            a0 = __fmaf_rn(xq.w, wA[4*q+3], a0);
            a1 = __fmaf_rn(xq.x, wB[4*q+0], a1);
            a1 = __fmaf_rn(xq.y, wB[4*q+1], a1);
            a1 = __fmaf_rn(xq.z, wB[4*q+2], a1);
            a1 = __fmaf_rn(xq.w, wB[4*q+3], a1);
        }
        const float c0 = __fadd_rn(a0, b1A);
        const float c1 = __fadd_rn(a1, b1B);

        // m1 = ((0.9f*m1) + cur1) - reset, each op rounded, no contraction
        mA = __fsub_rn(__fadd_rn(__fmul_rn(0.9f, mA), c0), rA);
        mB = __fsub_rn(__fadd_rn(__fmul_rn(0.9f, mB), c1), rB);

        const bool sA = mA > 1.0f;     // spike: (m1 - 1 > 0) <=> m1 > 1
        const bool sB = mB > 1.0f;
        rA = sA ? 1.0f : 0.0f;
        rB = sB ? 1.0f : 0.0f;

        const unsigned long long lo = __ballot(sA);   // bit li <-> h = li
        const unsigned long long hi = __ballot(sB);   // bit li <-> h = 64+li
        if (li == 0)
            masks[(size_t)t * B_TOTAL + b] = make_ulonglong2(lo, hi);
    };

    for (int t = 0; t < T_STEPS; t += 2) {
        substep(xc, xn, t);
        substep(xn, xc, t + 1);
    }
}

// ---------------------------------------------------------------------------
// Kernel B: layer-2. cur2[c] = sum of w2[c][h] over spiking h in ASCENDING h
// order with individually-rounded fp32 adds (exactly what BLAS fma(spk,w,acc)
// produces when spk is 0/1). Set-bit iteration via ctz keeps ascending order.
// Lane = (b, c); 64 b per block of 320 threads.
// ---------------------------------------------------------------------------
__global__ __launch_bounds__(320) void snn_l2(const ulonglong2* __restrict__ masks,
                                              const float* __restrict__ w2,
                                              const float* __restrict__ b2,
                                              float* __restrict__ out)
{
    __shared__ float w2s[H_DIM * 8];     // [h][8] padded, w2s[h*8+c] = w2[c][h]
    const int tid = threadIdx.x;
    for (int i = tid; i < C_OUT * H_DIM; i += 320) {
        const int c = i >> 7, h = i & 127;
        w2s[h * 8 + c] = w2[i];
    }
    const int b = blockIdx.x * 64 + tid / 5;
    const int c = tid % 5;
    const float b2c = b2[c];
    const float* wp = w2s + c;
    float m2 = 0.0f, r2 = 0.0f;
    __syncthreads();

    ulonglong2 mk = masks[b];            // t = 0
    for (int t = 0; t < T_STEPS; ++t) {
        ulonglong2 nx = mk;
        if (t + 1 < T_STEPS) nx = masks[(size_t)(t + 1) * B_TOTAL + b];

        float acc = 0.0f;
        uint32_t m0 = (uint32_t)(mk.x & 0xffffffffull);
        uint32_t m1 = (uint32_t)(mk.x >> 32);
        uint32_t mm2 = (uint32_t)(mk.y & 0xffffffffull);
        uint32_t m3 = (uint32_t)(mk.y >> 32);
        while (m0)  { int h = __builtin_ctz(m0);  m0  &= m0 - 1;  acc = __fadd_rn(acc, wp[(h      ) * 8]); }
        while (m1)  { int h = __builtin_ctz(m1);  m1  &= m1 - 1;  acc = __fadd_rn(acc, wp[(h + 32 ) * 8]); }
        while (mm2) { int h = __builtin_ctz(mm2); mm2 &= mm2 - 1; acc = __fadd_rn(acc, wp[(h + 64 ) * 8]); }
        while (m3)  { int h = __builtin_ctz(m3);  m3  &= m3 - 1;  acc = __fadd_rn(acc, wp[(h + 96 ) * 8]); }

        const float cur = __fadd_rn(acc, b2c);
        m2 = __fsub_rn(__fadd_rn(__fmul_rn(0.9f, m2), cur), r2);
        const float s = (m2 > 1.0f) ? 1.0f : 0.0f;
        r2 = s;
        // ((t*8192 + b)*5 + c) == t*40960 + blockIdx.x*320 + tid -> coalesced
        out[(size_t)t * (B_TOTAL * C_OUT) + (size_t)blockIdx.x * 320 + tid] = s;
        mk = nx;
    }
}

extern "C" void kernel_launch(void* const* d_in, const int* in_sizes, int n_in,
                              void* d_out, int out_size, void* d_ws, size_t ws_size,
                              hipStream_t stream) {
    const float* x  = (const float*)d_in[0];
    const float* w1 = (const float*)d_in[1];
    const float* b1 = (const float*)d_in[2];
    const float* w2 = (const float*)d_in[3];
    const float* b2 = (const float*)d_in[4];
    float* out = (float*)d_out;

    // spike masks [t][b], 16 B each: 8192*200*16 = 26.2 MB in d_ws
    ulonglong2* masks = (ulonglong2*)d_ws;

    snn_l1<<<dim3(B_TOTAL / 4), dim3(256), 0, stream>>>(x, w1, b1, masks);
    snn_l2<<<dim3(B_TOTAL / 64), dim3(320), 0, stream>>>(masks, w2, b2, out);
}

// Round 5
// 304.924 us; speedup vs baseline: 2.8128x; 2.8128x over previous
//
#include <hip/hip_runtime.h>
#include <cstdint>

#define T_STEPS 200
#define B_TOTAL 8192
#define F_IN    40
#define H_DIM   128
#define C_OUT   5

#define CH      8                         // time steps per staged chunk
#define NCHUNK  (T_STEPS / CH)            // 25
#define CHB     (CH * F_IN * 4)           // 1280 bytes per chunk per b
#define WIN     2048                      // staged window bytes (2 x 1024)
#define ROWB    (T_STEPS * F_IN * 4)      // 32000 bytes per b

// async global->LDS, 16B per lane, dest = wave-uniform base + lane*16
__device__ __forceinline__ void gload_lds16(const void* g, void* l) {
    __builtin_amdgcn_global_load_lds(
        (const __attribute__((address_space(1))) void*)g,
        (__attribute__((address_space(3))) void*)l, 16, 0, 0);
}

// ---------------------------------------------------------------------------
// Kernel A: layer-1 recurrence. Exact fp32 numerics (validated round 2):
// sequential-f FMA chain, +b1, then ((0.9*m)+cur)-reset, each op rounded.
// One wave per b; lane li owns h=li and h=li+64; ballots give the 128-bit
// spike mask in ascending-h order. x staged in per-wave-private LDS windows
// (8 steps deep) -> no __syncthreads, HBM latency hidden under 8 steps of
// compute.
// ---------------------------------------------------------------------------
__global__ __launch_bounds__(256, 3)
void snn_l1(const float* __restrict__ x,
            const float* __restrict__ w1,
            const float* __restrict__ b1,
            ulonglong2* __restrict__ masks)
{
    __shared__ __align__(16) char xs[2][4][WIN];   // 16 KiB

    const int li = threadIdx.x & 63;
    const int wv = threadIdx.x >> 6;
    const int b  = blockIdx.x * 4 + wv;
    const int hA = li, hB = li + 64;

    // w1 rows for this lane's two h, register-resident (80 VGPRs)
    float wA[F_IN], wB[F_IN];
    const float4* w1v = (const float4*)w1;
#pragma unroll
    for (int q = 0; q < 10; ++q) {
        float4 a = w1v[hA * 10 + q];
        wA[4*q+0] = a.x; wA[4*q+1] = a.y; wA[4*q+2] = a.z; wA[4*q+3] = a.w;
        float4 c = w1v[hB * 10 + q];
        wB[4*q+0] = c.x; wB[4*q+1] = c.y; wB[4*q+2] = c.z; wB[4*q+3] = c.w;
    }
    const float b1A = b1[hA], b1B = b1[hB];
    float mA = 0.0f, mB = 0.0f, rA = 0.0f, rB = 0.0f;

    // per-lane global src: row base + lane*16
    const char* xb = (const char*)x + (size_t)b * ROWB + (size_t)li * 16;

    // window start in bytes for chunk c (last window shifted back, in-bounds)
    auto winstart = [](int c) { return (c == NCHUNK - 1) ? (ROWB - WIN) : c * CHB; };

    // stage chunk 0 into buffer 0
    gload_lds16(xb + winstart(0),        &xs[0][wv][0]);
    gload_lds16(xb + winstart(0) + 1024, &xs[0][wv][1024]);
    asm volatile("s_waitcnt vmcnt(0)" ::: "memory");

    for (int c = 0; c < NCHUNK; ++c) {
        // prefetch next chunk into the other buffer (T14: issue early)
        if (c + 1 < NCHUNK) {
            const int ws = winstart(c + 1);
            gload_lds16(xb + ws,        &xs[(c + 1) & 1][wv][0]);
            gload_lds16(xb + ws + 1024, &xs[(c + 1) & 1][wv][1024]);
        }
        const int delta = c * CHB - winstart(c);       // 0, except last chunk
        const char* xsw = &xs[c & 1][wv][0];

#pragma unroll
        for (int s = 0; s < CH; ++s) {
            const float4* xrow = (const float4*)(xsw + delta + s * (F_IN * 4));
            float a0 = 0.0f, a1 = 0.0f;
#pragma unroll
            for (int q = 0; q < 10; ++q) {
                const float4 xq = xrow[q];             // ds_read_b128 broadcast
                a0 = __fmaf_rn(xq.x, wA[4*q+0], a0);
                a0 = __fmaf_rn(xq.y, wA[4*q+1], a0);
                a0 = __fmaf_rn(xq.z, wA[4*q+2], a0);
                a0 = __fmaf_rn(xq.w, wA[4*q+3], a0);
                a1 = __fmaf_rn(xq.x, wB[4*q+0], a1);
                a1 = __fmaf_rn(xq.y, wB[4*q+1], a1);
                a1 = __fmaf_rn(xq.z, wB[4*q+2], a1);
                a1 = __fmaf_rn(xq.w, wB[4*q+3], a1);
            }
            mA = __fsub_rn(__fadd_rn(__fmul_rn(0.9f, mA), __fadd_rn(a0, b1A)), rA);
            mB = __fsub_rn(__fadd_rn(__fmul_rn(0.9f, mB), __fadd_rn(a1, b1B)), rB);
            const bool sA = mA > 1.0f;                 // == (m-1 > 0) exactly
            const bool sB = mB > 1.0f;
            rA = sA ? 1.0f : 0.0f;
            rB = sB ? 1.0f : 0.0f;
            const unsigned long long lo = __ballot(sA);   // bit li <-> h=li
            const unsigned long long hi = __ballot(sB);   // bit li <-> h=64+li
            if (li == 0)
                masks[(size_t)(c * CH + s) * B_TOTAL + b] = make_ulonglong2(lo, hi);
        }
        // prefetch must have landed before we read the other buffer
        asm volatile("s_waitcnt vmcnt(0)" ::: "memory");
    }
}

// ---------------------------------------------------------------------------
// Kernel B: cur2 sums, parallel over (t,b). Ascending-h individually-rounded
// adds of w2[c][h] over spiking h — identical numerics to the validated
// round-2 l2 (fma with spk=0 leaves acc bit-exact).
// ---------------------------------------------------------------------------
__global__ __launch_bounds__(256)
void snn_l2a(const ulonglong2* __restrict__ masks,
             const float* __restrict__ w2,
             float* __restrict__ cur2)
{
    __shared__ float w2s[H_DIM * C_OUT];   // [h][c] for bank spread
    const int tid = threadIdx.x;
    for (int i = tid; i < H_DIM * C_OUT; i += 256) {
        const int c = i / H_DIM, h = i % H_DIM;
        w2s[h * C_OUT + c] = w2[i];
    }
    __syncthreads();

    const size_t gid = (size_t)blockIdx.x * 256 + tid;   // == t*B_TOTAL + b
    const ulonglong2 mk = masks[gid];
    float s0 = 0.f, s1 = 0.f, s2 = 0.f, s3 = 0.f, s4 = 0.f;

    auto acc32 = [&](uint32_t w, int base) {
        while (w) {
            const int h = base + __builtin_ctz(w);
            w &= w - 1;
            const float* wp = &w2s[h * C_OUT];
            s0 = __fadd_rn(s0, wp[0]);
            s1 = __fadd_rn(s1, wp[1]);
            s2 = __fadd_rn(s2, wp[2]);
            s3 = __fadd_rn(s3, wp[3]);
            s4 = __fadd_rn(s4, wp[4]);
        }
    };
    acc32((uint32_t)(mk.x & 0xffffffffull), 0);
    acc32((uint32_t)(mk.x >> 32), 32);
    acc32((uint32_t)(mk.y & 0xffffffffull), 64);
    acc32((uint32_t)(mk.y >> 32), 96);

    float* o = cur2 + gid * C_OUT;
    o[0] = s0; o[1] = s1; o[2] = s2; o[3] = s3; o[4] = s4;
}

// ---------------------------------------------------------------------------
// Kernel C: layer-2 recurrence over t. Lane = (b,c), coalesced cur2/out,
// depth-4 static-unrolled prefetch. Ops identical to validated round-2 l2.
// ---------------------------------------------------------------------------
__global__ __launch_bounds__(256)
void snn_l2b(const float* __restrict__ cur2,
             const float* __restrict__ b2,
             float* __restrict__ out)
{
    const int gid = blockIdx.x * 256 + threadIdx.x;      // b*5 + c
    const float b2c = b2[gid % 5];
    const int STRIDE = B_TOTAL * C_OUT;                  // 40960
    float m2 = 0.0f, r2 = 0.0f;

    float f0 = cur2[0 * (size_t)STRIDE + gid];
    float f1 = cur2[1 * (size_t)STRIDE + gid];
    float f2 = cur2[2 * (size_t)STRIDE + gid];
    float f3 = cur2[3 * (size_t)STRIDE + gid];

#define L2B_STEP(F, TT)                                                        \
    {                                                                          \
        const float cur = __fadd_rn(F, b2c);                                   \
        m2 = __fsub_rn(__fadd_rn(__fmul_rn(0.9f, m2), cur), r2);               \
        const float s = (m2 > 1.0f) ? 1.0f : 0.0f;                             \
        r2 = s;                                                                \
        out[(size_t)(TT) * STRIDE + gid] = s;                                  \
        F = ((TT) + 4 < T_STEPS) ? cur2[(size_t)((TT) + 4) * STRIDE + gid]     \
                                 : 0.0f;                                       \
    }

    for (int t = 0; t < T_STEPS; t += 4) {
        L2B_STEP(f0, t + 0)
        L2B_STEP(f1, t + 1)
        L2B_STEP(f2, t + 2)
        L2B_STEP(f3, t + 3)
    }
#undef L2B_STEP
}

extern "C" void kernel_launch(void* const* d_in, const int* in_sizes, int n_in,
                              void* d_out, int out_size, void* d_ws, size_t ws_size,
                              hipStream_t stream) {
    const float* x  = (const float*)d_in[0];
    const float* w1 = (const float*)d_in[1];
    const float* b1 = (const float*)d_in[2];
    const float* w2 = (const float*)d_in[3];
    const float* b2 = (const float*)d_in[4];
    float* out = (float*)d_out;

    // ws layout: masks [t][b] 16B each = 26,214,400 B; cur2 [t][b][c] fp32 =
    // 32,768,000 B; total ~59 MB.
    ulonglong2* masks = (ulonglong2*)d_ws;
    float* cur2 = (float*)((char*)d_ws + (size_t)T_STEPS * B_TOTAL * 16);

    snn_l1 <<<dim3(B_TOTAL / 4),            dim3(256), 0, stream>>>(x, w1, b1, masks);
    snn_l2a<<<dim3(T_STEPS * B_TOTAL / 256), dim3(256), 0, stream>>>(masks, w2, cur2);
    snn_l2b<<<dim3(B_TOTAL * C_OUT / 256),   dim3(256), 0, stream>>>(cur2, b2, out);
}

// Round 6
// 295.722 us; speedup vs baseline: 2.9004x; 1.0311x over previous
//
#include <hip/hip_runtime.h>
#include <cstdint>

#define T_STEPS 200
#define B_TOTAL 8192
#define F_IN    40
#define H_DIM   128
#define C_OUT   5

#define CH      8                         // time steps per staged chunk
#define NCHUNK  (T_STEPS / CH)            // 25
#define CHB     (CH * F_IN * 4)           // 1280 bytes per chunk per b
#define WIN     2048                      // staged window bytes (2 x 1024)
#define ROWB    (T_STEPS * F_IN * 4)      // 32000 bytes per b

typedef float v2f __attribute__((ext_vector_type(2)));
typedef float v4f __attribute__((ext_vector_type(4)));

// v_pk_fma_f32: D = S0*S1 + S2 per 32-bit lane of the pair (IEEE fp32 FMA,
// bit-identical to v_fma_f32). op_sel broadcasts one word of the x-pair to
// both result lanes, so (x_f,x_{f+1}) straight from ds_read_b128 feeds two
// consecutive f-steps with zero extra moves.
//   LO: both lanes read word0 of S0 (x_f)
//   HI: both lanes read word1 of S0 (x_{f+1})
#define PKFMA_LO(acc, xp, wp)                                                  \
    asm("v_pk_fma_f32 %0, %1, %2, %0 op_sel:[0,0,0] op_sel_hi:[0,1,1]"        \
        : "+v"(acc) : "v"(xp), "v"(wp))
#define PKFMA_HI(acc, xp, wp)                                                  \
    asm("v_pk_fma_f32 %0, %1, %2, %0 op_sel:[1,0,0] op_sel_hi:[1,1,1]"        \
        : "+v"(acc) : "v"(xp), "v"(wp))

// async global->LDS, 16B per lane, dest = wave-uniform base + lane*16
__device__ __forceinline__ void gload_lds16(const void* g, void* l) {
    __builtin_amdgcn_global_load_lds(
        (const __attribute__((address_space(1))) void*)g,
        (__attribute__((address_space(3))) void*)l, 16, 0, 0);
}

// ---------------------------------------------------------------------------
// Kernel A: layer-1 recurrence. Exact fp32 numerics (validated rounds 2/5):
// sequential-f FMA chain (f ascending), +b1, then ((0.9*m)+cur)-reset, each
// op individually rounded. One wave per b; lane li owns h=li (acc.x) and
// h=li+64 (acc.y); two ballots give the 128-bit spike mask in ascending-h
// order. x staged 8 steps deep in per-wave-private LDS windows (no barriers).
// ---------------------------------------------------------------------------
__global__ __launch_bounds__(256, 2)
void snn_l1(const float* __restrict__ x,
            const float* __restrict__ w1,
            const float* __restrict__ b1,
            ulonglong2* __restrict__ masks)
{
    __shared__ __align__(16) char xs[2][4][WIN];   // 16 KiB

    const int li = threadIdx.x & 63;
    const int wv = threadIdx.x >> 6;
    const int b  = blockIdx.x * 4 + wv;
    const int hA = li, hB = li + 64;

    // weights as interleaved pairs (wA_f, wB_f): 40 pairs = 80 VGPRs,
    // register-resident for the whole 200-step loop.
    v2f wab[F_IN];
    {
        const float* wArow = w1 + hA * F_IN;
        const float* wBrow = w1 + hB * F_IN;
#pragma unroll
        for (int f = 0; f < F_IN; ++f) {
            v2f p; p.x = wArow[f]; p.y = wBrow[f];
            wab[f] = p;
        }
    }
    const float b1A = b1[hA], b1B = b1[hB];
    float mA = 0.0f, mB = 0.0f, rA = 0.0f, rB = 0.0f;

    // per-lane global src: row base + lane*16
    const char* xb = (const char*)x + (size_t)b * ROWB + (size_t)li * 16;

    // window start in bytes for chunk c (last window shifted back, in-bounds)
    auto winstart = [](int c) { return (c == NCHUNK - 1) ? (ROWB - WIN) : c * CHB; };

    // stage chunk 0 into buffer 0
    gload_lds16(xb + winstart(0),        &xs[0][wv][0]);
    gload_lds16(xb + winstart(0) + 1024, &xs[0][wv][1024]);
    asm volatile("s_waitcnt vmcnt(0)" ::: "memory");

    ulonglong2* mp = masks + b;                    // strength-reduced store ptr

    for (int c = 0; c < NCHUNK; ++c) {
        // prefetch next chunk into the other buffer (issue early, wait late)
        if (c + 1 < NCHUNK) {
            const int ws = winstart(c + 1);
            gload_lds16(xb + ws,        &xs[(c + 1) & 1][wv][0]);
            gload_lds16(xb + ws + 1024, &xs[(c + 1) & 1][wv][1024]);
        }
        const int delta = c * CHB - winstart(c);   // 0, except last chunk
        const char* xsw = &xs[c & 1][wv][0];

#pragma unroll
        for (int s = 0; s < CH; ++s) {
            const v4f* xrow = (const v4f*)(xsw + delta + s * (F_IN * 4));
            v2f acc = {0.0f, 0.0f};
#pragma unroll
            for (int q = 0; q < 10; ++q) {
                const v4f xq = xrow[q];            // ds_read_b128 broadcast
                const v2f xlo = xq.lo, xhi = xq.hi;
                PKFMA_LO(acc, xlo, wab[4*q+0]);    // f = 4q
                PKFMA_HI(acc, xlo, wab[4*q+1]);    // f = 4q+1
                PKFMA_LO(acc, xhi, wab[4*q+2]);    // f = 4q+2
                PKFMA_HI(acc, xhi, wab[4*q+3]);    // f = 4q+3
            }
            mA = __fsub_rn(__fadd_rn(__fmul_rn(0.9f, mA), __fadd_rn(acc.x, b1A)), rA);
            mB = __fsub_rn(__fadd_rn(__fmul_rn(0.9f, mB), __fadd_rn(acc.y, b1B)), rB);
            const bool sA = mA > 1.0f;             // == (m-1 > 0) exactly
            const bool sB = mB > 1.0f;
            rA = sA ? 1.0f : 0.0f;
            rB = sB ? 1.0f : 0.0f;
            const unsigned long long lo = __ballot(sA);   // bit li <-> h=li
            const unsigned long long hi = __ballot(sB);   // bit li <-> h=64+li
            if (li == 0) *mp = make_ulonglong2(lo, hi);
            mp += B_TOTAL;
        }
        // prefetch must have landed before we read the other buffer
        asm volatile("s_waitcnt vmcnt(0)" ::: "memory");
    }
}

// ---------------------------------------------------------------------------
// Kernel B: cur2 sums, parallel over (t,b). Ascending-h individually-rounded
// adds of w2[c][h] over spiking h — identical numerics to the validated l2.
// ---------------------------------------------------------------------------
__global__ __launch_bounds__(256)
void snn_l2a(const ulonglong2* __restrict__ masks,
             const float* __restrict__ w2,
             float* __restrict__ cur2)
{
    __shared__ float w2s[H_DIM * C_OUT];   // [h][c] for bank spread
    const int tid = threadIdx.x;
    for (int i = tid; i < H_DIM * C_OUT; i += 256) {
        const int c = i / H_DIM, h = i % H_DIM;
        w2s[h * C_OUT + c] = w2[i];
    }
    __syncthreads();

    const size_t gid = (size_t)blockIdx.x * 256 + tid;   // == t*B_TOTAL + b
    const ulonglong2 mk = masks[gid];
    float s0 = 0.f, s1 = 0.f, s2 = 0.f, s3 = 0.f, s4 = 0.f;

    auto acc32 = [&](uint32_t w, int base) {
        while (w) {
            const int h = base + __builtin_ctz(w);
            w &= w - 1;
            const float* wp = &w2s[h * C_OUT];
            s0 = __fadd_rn(s0, wp[0]);
            s1 = __fadd_rn(s1, wp[1]);
            s2 = __fadd_rn(s2, wp[2]);
            s3 = __fadd_rn(s3, wp[3]);
            s4 = __fadd_rn(s4, wp[4]);
        }
    };
    acc32((uint32_t)(mk.x & 0xffffffffull), 0);
    acc32((uint32_t)(mk.x >> 32), 32);
    acc32((uint32_t)(mk.y & 0xffffffffull), 64);
    acc32((uint32_t)(mk.y >> 32), 96);

    float* o = cur2 + gid * C_OUT;
    o[0] = s0; o[1] = s1; o[2] = s2; o[3] = s3; o[4] = s4;
}

// ---------------------------------------------------------------------------
// Kernel C: layer-2 recurrence over t. Lane = (b,c), coalesced cur2/out,
// depth-4 static-unrolled prefetch. Ops identical to validated l2.
// ---------------------------------------------------------------------------
__global__ __launch_bounds__(256)
void snn_l2b(const float* __restrict__ cur2,
             const float* __restrict__ b2,
             float* __restrict__ out)
{
    const int gid = blockIdx.x * 256 + threadIdx.x;      // b*5 + c
    const float b2c = b2[gid % 5];
    const int STRIDE = B_TOTAL * C_OUT;                  // 40960
    float m2 = 0.0f, r2 = 0.0f;

    float f0 = cur2[0 * (size_t)STRIDE + gid];
    float f1 = cur2[1 * (size_t)STRIDE + gid];
    float f2 = cur2[2 * (size_t)STRIDE + gid];
    float f3 = cur2[3 * (size_t)STRIDE + gid];

#define L2B_STEP(F, TT)                                                        \
    {                                                                          \
        const float cur = __fadd_rn(F, b2c);                                   \
        m2 = __fsub_rn(__fadd_rn(__fmul_rn(0.9f, m2), cur), r2);               \
        const float s = (m2 > 1.0f) ? 1.0f : 0.0f;                             \
        r2 = s;                                                                \
        out[(size_t)(TT) * STRIDE + gid] = s;                                  \
        F = ((TT) + 4 < T_STEPS) ? cur2[(size_t)((TT) + 4) * STRIDE + gid]     \
                                 : 0.0f;                                       \
    }

    for (int t = 0; t < T_STEPS; t += 4) {
        L2B_STEP(f0, t + 0)
        L2B_STEP(f1, t + 1)
        L2B_STEP(f2, t + 2)
        L2B_STEP(f3, t + 3)
    }
#undef L2B_STEP
}

extern "C" void kernel_launch(void* const* d_in, const int* in_sizes, int n_in,
                              void* d_out, int out_size, void* d_ws, size_t ws_size,
                              hipStream_t stream) {
    const float* x  = (const float*)d_in[0];
    const float* w1 = (const float*)d_in[1];
    const float* b1 = (const float*)d_in[2];
    const float* w2 = (const float*)d_in[3];
    const float* b2 = (const float*)d_in[4];
    float* out = (float*)d_out;

    // ws layout: masks [t][b] 16B each = 26,214,400 B; cur2 [t][b][c] fp32 =
    // 32,768,000 B; total ~59 MB.
    ulonglong2* masks = (ulonglong2*)d_ws;
    float* cur2 = (float*)((char*)d_ws + (size_t)T_STEPS * B_TOTAL * 16);

    snn_l1 <<<dim3(B_TOTAL / 4),             dim3(256), 0, stream>>>(x, w1, b1, masks);
    snn_l2a<<<dim3(T_STEPS * B_TOTAL / 256), dim3(256), 0, stream>>>(masks, w2, cur2);
    snn_l2b<<<dim3(B_TOTAL * C_OUT / 256),   dim3(256), 0, stream>>>(cur2, b2, out);
}

// Round 7
// 292.225 us; speedup vs baseline: 2.9351x; 1.0120x over previous
//
#include <hip/hip_runtime.h>
#include <cstdint>

#define T_STEPS 200
#define B_TOTAL 8192
#define F_IN    40
#define H_DIM   128
#define C_OUT   5

#define CH      8                         // time steps per staged chunk
#define NCHUNK  (T_STEPS / CH)            // 25
#define CHB     (CH * F_IN * 4)           // 1280 bytes per chunk per b
#define WIN     2048                      // staged window bytes (2 x 1024)
#define ROWB    (T_STEPS * F_IN * 4)      // 32000 bytes per b

typedef float v2f __attribute__((ext_vector_type(2)));
typedef float v4f __attribute__((ext_vector_type(4)));

// v_pk_fma_f32: D = S0*S1 + S2 per 32-bit lane of the pair (IEEE fp32 FMA,
// bit-identical to v_fma_f32). op_sel broadcasts one word of the x-pair to
// both result lanes: LO -> word0 (x_f), HI -> word1 (x_{f+1}).
#define PKFMA_LO(acc, xp, wp)                                                  \
    asm("v_pk_fma_f32 %0, %1, %2, %0 op_sel:[0,0,0] op_sel_hi:[0,1,1]"        \
        : "+v"(acc) : "v"(xp), "v"(wp))
#define PKFMA_HI(acc, xp, wp)                                                  \
    asm("v_pk_fma_f32 %0, %1, %2, %0 op_sel:[1,0,0] op_sel_hi:[1,1,1]"        \
        : "+v"(acc) : "v"(xp), "v"(wp))

// async global->LDS, 16B per lane, dest = wave-uniform base + lane*16
__device__ __forceinline__ void gload_lds16(const void* g, void* l) {
    __builtin_amdgcn_global_load_lds(
        (const __attribute__((address_space(1))) void*)g,
        (__attribute__((address_space(3))) void*)l, 16, 0, 0);
}

// ---------------------------------------------------------------------------
// Kernel A: layer-1 recurrence. Exact fp32 numerics (validated rounds 2/5/6):
// per-step sequential-f FMA chain (f = 0..39), +b1, then ((0.9*m)+cur)-reset,
// each op individually rounded. One wave per b; lane li owns h=li (acc.x) and
// h=li+64 (acc.y); two ballots give the 128-bit spike mask in ascending-h
// order. x staged 8 steps deep in per-wave-private LDS windows (no barriers).
// Steps processed in pairs: two independent 40-deep FMA chains in flight.
// Weights pinned to VGPRs via opaque asm (compiler otherwise rematerializes
// them from global inside the loop — round-6 VGPR=60 showed that).
// ---------------------------------------------------------------------------
__global__ __launch_bounds__(256, 4)
void snn_l1(const float* __restrict__ x,
            const float* __restrict__ w1,
            const float* __restrict__ b1,
            ulonglong2* __restrict__ masks)
{
    __shared__ __align__(16) char xs[2][4][WIN];   // 16 KiB

    const int li = threadIdx.x & 63;
    const int wv = threadIdx.x >> 6;
    const int b  = blockIdx.x * 4 + wv;
    const int hA = li, hB = li + 64;

    // weights as interleaved pairs (wA_f, wB_f): 40 pairs = 80 VGPRs
    v2f wab[F_IN];
    {
        const float* wArow = w1 + hA * F_IN;
        const float* wBrow = w1 + hB * F_IN;
#pragma unroll
        for (int f = 0; f < F_IN; ++f) {
            v2f p; p.x = wArow[f]; p.y = wBrow[f];
            wab[f] = p;
        }
    }
    // Pin: make each weight pair opaque so the compiler cannot rematerialize
    // it from the w1 load inside the loop; forces true register residency.
#pragma unroll
    for (int f = 0; f < F_IN; ++f) asm("" : "+v"(wab[f]));

    const float b1A = b1[hA], b1B = b1[hB];
    float mA = 0.0f, mB = 0.0f, rA = 0.0f, rB = 0.0f;

    // per-lane global src: row base + lane*16
    const char* xb = (const char*)x + (size_t)b * ROWB + (size_t)li * 16;

    // window start in bytes for chunk c (last window shifted back, in-bounds)
    auto winstart = [](int c) { return (c == NCHUNK - 1) ? (ROWB - WIN) : c * CHB; };

    // stage chunk 0 into buffer 0
    gload_lds16(xb + winstart(0),        &xs[0][wv][0]);
    gload_lds16(xb + winstart(0) + 1024, &xs[0][wv][1024]);
    asm volatile("s_waitcnt vmcnt(0)" ::: "memory");

    ulonglong2* mp = masks + b;                    // strength-reduced store ptr

    for (int c = 0; c < NCHUNK; ++c) {
        // prefetch next chunk into the other buffer (issue early, wait late)
        if (c + 1 < NCHUNK) {
            const int ws = winstart(c + 1);
            gload_lds16(xb + ws,        &xs[(c + 1) & 1][wv][0]);
            gload_lds16(xb + ws + 1024, &xs[(c + 1) & 1][wv][1024]);
        }
        const int delta = c * CHB - winstart(c);   // 0, except last chunk
        const char* xsw = &xs[c & 1][wv][0];

#pragma unroll
        for (int sp = 0; sp < CH; sp += 2) {
            const v4f* xr0 = (const v4f*)(xsw + delta + (sp + 0) * (F_IN * 4));
            const v4f* xr1 = (const v4f*)(xsw + delta + (sp + 1) * (F_IN * 4));
            v2f acc0 = {0.0f, 0.0f};
            v2f acc1 = {0.0f, 0.0f};
            // Two independent sequential-f chains (steps sp, sp+1) in flight;
            // within each chain the f-order is 0..39 -> bit-exact.
#pragma unroll
            for (int q = 0; q < 10; ++q) {
                const v4f x0 = xr0[q];             // ds_read_b128 broadcast
                const v4f x1 = xr1[q];
                const v2f x0lo = x0.lo, x0hi = x0.hi;
                const v2f x1lo = x1.lo, x1hi = x1.hi;
                PKFMA_LO(acc0, x0lo, wab[4*q+0]);
                PKFMA_LO(acc1, x1lo, wab[4*q+0]);
                PKFMA_HI(acc0, x0lo, wab[4*q+1]);
                PKFMA_HI(acc1, x1lo, wab[4*q+1]);
                PKFMA_LO(acc0, x0hi, wab[4*q+2]);
                PKFMA_LO(acc1, x1hi, wab[4*q+2]);
                PKFMA_HI(acc0, x0hi, wab[4*q+3]);
                PKFMA_HI(acc1, x1hi, wab[4*q+3]);
            }
            // step sp
            mA = __fsub_rn(__fadd_rn(__fmul_rn(0.9f, mA), __fadd_rn(acc0.x, b1A)), rA);
            mB = __fsub_rn(__fadd_rn(__fmul_rn(0.9f, mB), __fadd_rn(acc0.y, b1B)), rB);
            bool sA = mA > 1.0f, sB = mB > 1.0f;
            rA = sA ? 1.0f : 0.0f;
            rB = sB ? 1.0f : 0.0f;
            unsigned long long lo = __ballot(sA);
            unsigned long long hi = __ballot(sB);
            if (li == 0) *mp = make_ulonglong2(lo, hi);
            mp += B_TOTAL;
            // step sp+1
            mA = __fsub_rn(__fadd_rn(__fmul_rn(0.9f, mA), __fadd_rn(acc1.x, b1A)), rA);
            mB = __fsub_rn(__fadd_rn(__fmul_rn(0.9f, mB), __fadd_rn(acc1.y, b1B)), rB);
            sA = mA > 1.0f; sB = mB > 1.0f;
            rA = sA ? 1.0f : 0.0f;
            rB = sB ? 1.0f : 0.0f;
            lo = __ballot(sA);
            hi = __ballot(sB);
            if (li == 0) *mp = make_ulonglong2(lo, hi);
            mp += B_TOTAL;
        }
        // prefetch must have landed before we read the other buffer
        asm volatile("s_waitcnt vmcnt(0)" ::: "memory");
    }
}

// ---------------------------------------------------------------------------
// Kernel B: cur2 sums, parallel over (t,b). Ascending-h individually-rounded
// adds of w2[c][h] over spiking h — identical numerics to the validated l2.
// ---------------------------------------------------------------------------
__global__ __launch_bounds__(256)
void snn_l2a(const ulonglong2* __restrict__ masks,
             const float* __restrict__ w2,
             float* __restrict__ cur2)
{
    __shared__ float w2s[H_DIM * C_OUT];   // [h][c] for bank spread
    const int tid = threadIdx.x;
    for (int i = tid; i < H_DIM * C_OUT; i += 256) {
        const int c = i / H_DIM, h = i % H_DIM;
        w2s[h * C_OUT + c] = w2[i];
    }
    __syncthreads();

    const size_t gid = (size_t)blockIdx.x * 256 + tid;   // == t*B_TOTAL + b
    const ulonglong2 mk = masks[gid];
    float s0 = 0.f, s1 = 0.f, s2 = 0.f, s3 = 0.f, s4 = 0.f;

    auto acc32 = [&](uint32_t w, int base) {
        while (w) {
            const int h = base + __builtin_ctz(w);
            w &= w - 1;
            const float* wp = &w2s[h * C_OUT];
            s0 = __fadd_rn(s0, wp[0]);
            s1 = __fadd_rn(s1, wp[1]);
            s2 = __fadd_rn(s2, wp[2]);
            s3 = __fadd_rn(s3, wp[3]);
            s4 = __fadd_rn(s4, wp[4]);
        }
    };
    acc32((uint32_t)(mk.x & 0xffffffffull), 0);
    acc32((uint32_t)(mk.x >> 32), 32);
    acc32((uint32_t)(mk.y & 0xffffffffull), 64);
    acc32((uint32_t)(mk.y >> 32), 96);

    float* o = cur2 + gid * C_OUT;
    o[0] = s0; o[1] = s1; o[2] = s2; o[3] = s3; o[4] = s4;
}

// ---------------------------------------------------------------------------
// Kernel C: layer-2 recurrence over t. Lane = (b,c), coalesced cur2/out,
// depth-4 static-unrolled prefetch. Ops identical to validated l2.
// ---------------------------------------------------------------------------
__global__ __launch_bounds__(256)
void snn_l2b(const float* __restrict__ cur2,
             const float* __restrict__ b2,
             float* __restrict__ out)
{
    const int gid = blockIdx.x * 256 + threadIdx.x;      // b*5 + c
    const float b2c = b2[gid % 5];
    const int STRIDE = B_TOTAL * C_OUT;                  // 40960
    float m2 = 0.0f, r2 = 0.0f;

    float f0 = cur2[0 * (size_t)STRIDE + gid];
    float f1 = cur2[1 * (size_t)STRIDE + gid];
    float f2 = cur2[2 * (size_t)STRIDE + gid];
    float f3 = cur2[3 * (size_t)STRIDE + gid];

#define L2B_STEP(F, TT)                                                        \
    {                                                                          \
        const float cur = __fadd_rn(F, b2c);                                   \
        m2 = __fsub_rn(__fadd_rn(__fmul_rn(0.9f, m2), cur), r2);               \
        const float s = (m2 > 1.0f) ? 1.0f : 0.0f;                             \
        r2 = s;                                                                \
        out[(size_t)(TT) * STRIDE + gid] = s;                                  \
        F = ((TT) + 4 < T_STEPS) ? cur2[(size_t)((TT) + 4) * STRIDE + gid]     \
                                 : 0.0f;                                       \
    }

    for (int t = 0; t < T_STEPS; t += 4) {
        L2B_STEP(f0, t + 0)
        L2B_STEP(f1, t + 1)
        L2B_STEP(f2, t + 2)
        L2B_STEP(f3, t + 3)
    }
#undef L2B_STEP
}

extern "C" void kernel_launch(void* const* d_in, const int* in_sizes, int n_in,
                              void* d_out, int out_size, void* d_ws, size_t ws_size,
                              hipStream_t stream) {
    const float* x  = (const float*)d_in[0];
    const float* w1 = (const float*)d_in[1];
    const float* b1 = (const float*)d_in[2];
    const float* w2 = (const float*)d_in[3];
    const float* b2 = (const float*)d_in[4];
    float* out = (float*)d_out;

    // ws layout: masks [t][b] 16B each = 26,214,400 B; cur2 [t][b][c] fp32 =
    // 32,768,000 B; total ~59 MB.
    ulonglong2* masks = (ulonglong2*)d_ws;
    float* cur2 = (float*)((char*)d_ws + (size_t)T_STEPS * B_TOTAL * 16);

    snn_l1 <<<dim3(B_TOTAL / 4),             dim3(256), 0, stream>>>(x, w1, b1, masks);
    snn_l2a<<<dim3(T_STEPS * B_TOTAL / 256), dim3(256), 0, stream>>>(masks, w2, cur2);
    snn_l2b<<<dim3(B_TOTAL * C_OUT / 256),   dim3(256), 0, stream>>>(cur2, b2, out);
}

// Round 9
// 289.125 us; speedup vs baseline: 2.9665x; 1.0107x over previous
//
#include <hip/hip_runtime.h>
#include <cstdint>

#define T_STEPS 200
#define B_TOTAL 8192
#define F_IN    40
#define H_DIM   128
#define C_OUT   5

#define CH      8                         // time steps per staged chunk
#define NCHUNK  (T_STEPS / CH)            // 25
#define CHB     (CH * F_IN * 4)           // 1280 bytes per chunk per b
#define WIN     2048                      // staged window bytes (2 x 1024)
#define ROWB    (T_STEPS * F_IN * 4)      // 32000 bytes per b

typedef float v2f __attribute__((ext_vector_type(2)));
typedef float v4f __attribute__((ext_vector_type(4)));

// v_pk_fma_f32: D = S0*S1 + S2 per 32-bit lane of the pair (IEEE fp32 FMA,
// bit-identical to v_fma_f32). op_sel broadcasts one word of the x-pair to
// both result lanes: LO -> word0 (x_f), HI -> word1 (x_{f+1}).
#define PKFMA_LO(acc, xp, wp)                                                  \
    asm("v_pk_fma_f32 %0, %1, %2, %0 op_sel:[0,0,0] op_sel_hi:[0,1,1]"        \
        : "+v"(acc) : "v"(xp), "v"(wp))
#define PKFMA_HI(acc, xp, wp)                                                  \
    asm("v_pk_fma_f32 %0, %1, %2, %0 op_sel:[1,0,0] op_sel_hi:[1,1,1]"        \
        : "+v"(acc) : "v"(xp), "v"(wp))

// async global->LDS, 16B per lane, dest = wave-uniform base + lane*16
__device__ __forceinline__ void gload_lds16(const void* g, void* l) {
    __builtin_amdgcn_global_load_lds(
        (const __attribute__((address_space(1))) void*)g,
        (__attribute__((address_space(3))) void*)l, 16, 0, 0);
}

// ---------------------------------------------------------------------------
// Kernel A: layer-1 recurrence. Exact fp32 numerics (validated r2/r5/r6/r7):
// per-step sequential-f FMA chain (f = 0..39), +b1, then ((0.9*m)+cur)-reset,
// each op individually rounded. One wave per b; lane li owns h=li (acc.x) and
// h=li+64 (acc.y); two ballots give the 128-bit spike mask in ascending-h
// order. x staged 8 steps deep in per-wave-private LDS windows (no barriers).
// Weight residency forced: volatile asm pins (cannot be duplicated/remat'd)
// + waves_per_eu(4,4) so the allocator budgets 128 VGPRs instead of
// squeezing to 64 and reloading w1 every step (r6/r7 failure mode).
// ---------------------------------------------------------------------------
__global__ __launch_bounds__(256)
__attribute__((amdgpu_waves_per_eu(4, 4)))
void snn_l1(const float* __restrict__ x,
            const float* __restrict__ w1,
            const float* __restrict__ b1,
            ulonglong2* __restrict__ masks)
{
    __shared__ __align__(16) char xs[2][4][WIN];   // 16 KiB

    const int li = threadIdx.x & 63;
    const int wv = threadIdx.x >> 6;
    const int b  = blockIdx.x * 4 + wv;
    const int hA = li, hB = li + 64;

    // weights as interleaved pairs (wA_f, wB_f): 40 pairs = 80 VGPRs
    v2f wab[F_IN];
    {
        const float* wArow = w1 + hA * F_IN;
        const float* wBrow = w1 + hB * F_IN;
#pragma unroll
        for (int f = 0; f < F_IN; ++f) {
            v2f p; p.x = wArow[f]; p.y = wBrow[f];
            wab[f] = p;
        }
    }
    // Volatile pin: executes exactly once; output is opaque -> the loop must
    // keep all 40 pairs live in VGPRs (no remat from w1, no duplication).
#pragma unroll
    for (int f = 0; f < F_IN; ++f) asm volatile("" : "+v"(wab[f]));

    const float b1A = b1[hA], b1B = b1[hB];
    float mA = 0.0f, mB = 0.0f, rA = 0.0f, rB = 0.0f;

    // per-lane global src: row base + lane*16
    const char* xb = (const char*)x + (size_t)b * ROWB + (size_t)li * 16;

    // window start in bytes for chunk c (last window shifted back, in-bounds)
    auto winstart = [](int c) { return (c == NCHUNK - 1) ? (ROWB - WIN) : c * CHB; };

    // stage chunk 0 into buffer 0
    gload_lds16(xb + winstart(0),        &xs[0][wv][0]);
    gload_lds16(xb + winstart(0) + 1024, &xs[0][wv][1024]);
    asm volatile("s_waitcnt vmcnt(0)" ::: "memory");

    ulonglong2* mp = masks + b;                    // strength-reduced store ptr

    for (int c = 0; c < NCHUNK; ++c) {
        // prefetch next chunk into the other buffer (issue early, wait late)
        if (c + 1 < NCHUNK) {
            const int ws = winstart(c + 1);
            gload_lds16(xb + ws,        &xs[(c + 1) & 1][wv][0]);
            gload_lds16(xb + ws + 1024, &xs[(c + 1) & 1][wv][1024]);
        }
        const int delta = c * CHB - winstart(c);   // 0, except last chunk
        const char* xsw = &xs[c & 1][wv][0];

#pragma unroll
        for (int sp = 0; sp < CH; sp += 2) {
            const v4f* xr0 = (const v4f*)(xsw + delta + (sp + 0) * (F_IN * 4));
            const v4f* xr1 = (const v4f*)(xsw + delta + (sp + 1) * (F_IN * 4));
            v2f acc0 = {0.0f, 0.0f};
            v2f acc1 = {0.0f, 0.0f};
            // Two independent sequential-f chains (steps sp, sp+1) in flight;
            // within each chain the f-order is 0..39 -> bit-exact.
#pragma unroll
            for (int q = 0; q < 10; ++q) {
                const v4f x0 = xr0[q];             // ds_read_b128 broadcast
                const v4f x1 = xr1[q];
                const v2f x0lo = x0.lo, x0hi = x0.hi;
                const v2f x1lo = x1.lo, x1hi = x1.hi;
                PKFMA_LO(acc0, x0lo, wab[4*q+0]);
                PKFMA_LO(acc1, x1lo, wab[4*q+0]);
                PKFMA_HI(acc0, x0lo, wab[4*q+1]);
                PKFMA_HI(acc1, x1lo, wab[4*q+1]);
                PKFMA_LO(acc0, x0hi, wab[4*q+2]);
                PKFMA_LO(acc1, x1hi, wab[4*q+2]);
                PKFMA_HI(acc0, x0hi, wab[4*q+3]);
                PKFMA_HI(acc1, x1hi, wab[4*q+3]);
            }
            // step sp
            mA = __fsub_rn(__fadd_rn(__fmul_rn(0.9f, mA), __fadd_rn(acc0.x, b1A)), rA);
            mB = __fsub_rn(__fadd_rn(__fmul_rn(0.9f, mB), __fadd_rn(acc0.y, b1B)), rB);
            bool sA = mA > 1.0f, sB = mB > 1.0f;
            rA = sA ? 1.0f : 0.0f;
            rB = sB ? 1.0f : 0.0f;
            unsigned long long lo = __ballot(sA);
            unsigned long long hi = __ballot(sB);
            if (li == 0) *mp = make_ulonglong2(lo, hi);
            mp += B_TOTAL;
            // step sp+1
            mA = __fsub_rn(__fadd_rn(__fmul_rn(0.9f, mA), __fadd_rn(acc1.x, b1A)), rA);
            mB = __fsub_rn(__fadd_rn(__fmul_rn(0.9f, mB), __fadd_rn(acc1.y, b1B)), rB);
            sA = mA > 1.0f; sB = mB > 1.0f;
            rA = sA ? 1.0f : 0.0f;
            rB = sB ? 1.0f : 0.0f;
            lo = __ballot(sA);
            hi = __ballot(sB);
            if (li == 0) *mp = make_ulonglong2(lo, hi);
            mp += B_TOTAL;
        }
        // prefetch must have landed before we read the other buffer
        asm volatile("s_waitcnt vmcnt(0)" ::: "memory");
    }
}

// ---------------------------------------------------------------------------
// Kernel B: cur2 sums, parallel over (t,b). Ascending-h individually-rounded
// adds of w2[c][h] over spiking h — identical numerics to the validated l2.
// ---------------------------------------------------------------------------
__global__ __launch_bounds__(256)
void snn_l2a(const ulonglong2* __restrict__ masks,
             const float* __restrict__ w2,
             float* __restrict__ cur2)
{
    __shared__ float w2s[H_DIM * C_OUT];   // [h][c] for bank spread
    const int tid = threadIdx.x;
    for (int i = tid; i < H_DIM * C_OUT; i += 256) {
        const int c = i / H_DIM, h = i % H_DIM;
        w2s[h * C_OUT + c] = w2[i];
    }
    __syncthreads();

    const size_t gid = (size_t)blockIdx.x * 256 + tid;   // == t*B_TOTAL + b
    const ulonglong2 mk = masks[gid];
    float s0 = 0.f, s1 = 0.f, s2 = 0.f, s3 = 0.f, s4 = 0.f;

    auto acc32 = [&](uint32_t w, int base) {
        while (w) {
            const int h = base + __builtin_ctz(w);
            w &= w - 1;
            const float* wp = &w2s[h * C_OUT];
            s0 = __fadd_rn(s0, wp[0]);
            s1 = __fadd_rn(s1, wp[1]);
            s2 = __fadd_rn(s2, wp[2]);
            s3 = __fadd_rn(s3, wp[3]);
            s4 = __fadd_rn(s4, wp[4]);
        }
    };
    acc32((uint32_t)(mk.x & 0xffffffffull), 0);
    acc32((uint32_t)(mk.x >> 32), 32);
    acc32((uint32_t)(mk.y & 0xffffffffull), 64);
    acc32((uint32_t)(mk.y >> 32), 96);

    float* o = cur2 + gid * C_OUT;
    o[0] = s0; o[1] = s1; o[2] = s2; o[3] = s3; o[4] = s4;
}

// ---------------------------------------------------------------------------
// Kernel C: layer-2 recurrence over t. Lane = (b,c), coalesced cur2/out,
// depth-4 static-unrolled prefetch. Ops identical to validated l2.
// ---------------------------------------------------------------------------
__global__ __launch_bounds__(256)
void snn_l2b(const float* __restrict__ cur2,
             const float* __restrict__ b2,
             float* __restrict__ out)
{
    const int gid = blockIdx.x * 256 + threadIdx.x;      // b*5 + c
    const float b2c = b2[gid % 5];
    const int STRIDE = B_TOTAL * C_OUT;                  // 40960
    float m2 = 0.0f, r2 = 0.0f;

    float f0 = cur2[0 * (size_t)STRIDE + gid];
    float f1 = cur2[1 * (size_t)STRIDE + gid];
    float f2 = cur2[2 * (size_t)STRIDE + gid];
    float f3 = cur2[3 * (size_t)STRIDE + gid];

#define L2B_STEP(F, TT)                                                        \
    {                                                                          \
        const float cur = __fadd_rn(F, b2c);                                   \
        m2 = __fsub_rn(__fadd_rn(__fmul_rn(0.9f, m2), cur), r2);               \
        const float s = (m2 > 1.0f) ? 1.0f : 0.0f;                             \
        r2 = s;                                                                \
        out[(size_t)(TT) * STRIDE + gid] = s;                                  \
        F = ((TT) + 4 < T_STEPS) ? cur2[(size_t)((TT) + 4) * STRIDE + gid]     \
                                 : 0.0f;                                       \
    }

    for (int t = 0; t < T_STEPS; t += 4) {
        L2B_STEP(f0, t + 0)
        L2B_STEP(f1, t + 1)
        L2B_STEP(f2, t + 2)
        L2B_STEP(f3, t + 3)
    }
#undef L2B_STEP
}

extern "C" void kernel_launch(void* const* d_in, const int* in_sizes, int n_in,
                              void* d_out, int out_size, void* d_ws, size_t ws_size,
                              hipStream_t stream) {
    const float* x  = (const float*)d_in[0];
    const float* w1 = (const float*)d_in[1];
    const float* b1 = (const float*)d_in[2];
    const float* w2 = (const float*)d_in[3];
    const float* b2 = (const float*)d_in[4];
    float* out = (float*)d_out;

    // ws layout: masks [t][b] 16B each = 26,214,400 B; cur2 [t][b][c] fp32 =
    // 32,768,000 B; total ~59 MB.
    ulonglong2* masks = (ulonglong2*)d_ws;
    float* cur2 = (float*)((char*)d_ws + (size_t)T_STEPS * B_TOTAL * 16);

    snn_l1 <<<dim3(B_TOTAL / 4),             dim3(256), 0, stream>>>(x, w1, b1, masks);
    snn_l2a<<<dim3(T_STEPS * B_TOTAL / 256), dim3(256), 0, stream>>>(masks, w2, cur2);
    snn_l2b<<<dim3(B_TOTAL * C_OUT / 256),   dim3(256), 0, stream>>>(cur2, b2, out);
}